// Round 1
// baseline (629.868 us; speedup 1.0000x reference)
//
#include <hip/hip_runtime.h>
#include <math.h>

#define NEG_SLOPE 0.2f
#define BN_EPS_F 1e-5f
#define NUM_G 500

__device__ __forceinline__ float leaky(float x){ return x > 0.f ? x : NEG_SLOPE*x; }
__device__ __forceinline__ float sel4(int h, float a, float b, float c, float d){
  float r = a; r = (h==1)? b : r; r = (h==2)? c : r; r = (h==3)? d : r; return r;
}

// ---------------- linear 1: xh1 = x @ W1, plus per-head att dots ----------------
__global__ __launch_bounds__(256) void lin1_kernel(
    const float* __restrict__ x, const float* __restrict__ W,
    const float* __restrict__ att_s, const float* __restrict__ att_d,
    float* __restrict__ xh, float* __restrict__ a_src, float* __restrict__ a_dst, int N)
{
  __shared__ float Ws[32*64];
  __shared__ float xs[4][32];
  int tid = threadIdx.x;
  for (int i = tid; i < 32*64; i += 256) Ws[i] = W[i];
  int sub = tid >> 6, lane = tid & 63;
  float asv = att_s[lane];   // att_src1 flat [4*16] == lane index
  float adv = att_d[lane];
  int h = lane >> 4, c = lane & 15;
  for (int it = 0; it < 4; ++it) {
    int node = blockIdx.x*16 + it*4 + sub;
    __syncthreads();
    if (node < N && lane < 32) xs[sub][lane] = x[(size_t)node*32 + lane];
    __syncthreads();
    float acc = 0.f;
    #pragma unroll
    for (int k = 0; k < 32; ++k) acc += xs[sub][k] * Ws[k*64 + lane];
    float sv = acc*asv, dv = acc*adv;
    #pragma unroll
    for (int msk = 1; msk < 16; msk <<= 1) { sv += __shfl_xor(sv, msk); dv += __shfl_xor(dv, msk); }
    if (node < N) {
      xh[(size_t)node*64 + lane] = acc;
      if (c == 0) { a_src[node*4 + h] = sv; a_dst[node*4 + h] = dv; }
    }
  }
}

// ---------------- linear 2: xh2 = h1 @ W2, plus att dots ----------------
__global__ __launch_bounds__(256) void lin2_kernel(
    const float* __restrict__ hin, const float* __restrict__ W,
    const float* __restrict__ att_s, const float* __restrict__ att_d,
    float* __restrict__ xh, float* __restrict__ a_src, float* __restrict__ a_dst, int N)
{
  __shared__ float Ws[64*128];      // 32 KiB
  __shared__ float hs[2][64];
  int tid = threadIdx.x;
  for (int i = tid; i < 64*128; i += 256) Ws[i] = W[i];
  int sub = tid >> 7, lane2 = tid & 127;
  float asv = att_s[lane2];  // att_src2 flat [4*32] == lane2 index
  float adv = att_d[lane2];
  int h = lane2 >> 5;
  for (int it = 0; it < 8; ++it) {
    int node = blockIdx.x*16 + it*2 + sub;
    __syncthreads();
    if (node < N && lane2 < 64) hs[sub][lane2] = hin[(size_t)node*64 + lane2];
    __syncthreads();
    float acc = 0.f;
    #pragma unroll
    for (int k = 0; k < 64; ++k) acc += hs[sub][k] * Ws[k*128 + lane2];
    float sv = acc*asv, dv = acc*adv;
    #pragma unroll
    for (int msk = 1; msk < 32; msk <<= 1) { sv += __shfl_xor(sv, msk); dv += __shfl_xor(dv, msk); }
    if (node < N) {
      xh[(size_t)node*128 + lane2] = acc;
      if ((lane2 & 31) == 0) { a_src[node*4 + h] = sv; a_dst[node*4 + h] = dv; }
    }
  }
}

// ---------------- histogram (used for deg-by-dst and batch counts) ----------------
__global__ void hist_kernel(const int* __restrict__ idx, int* __restrict__ cnt, int n)
{
  int i = blockIdx.x*blockDim.x + threadIdx.x;
  int stride = gridDim.x*blockDim.x;
  for (; i < n; i += stride) atomicAdd(&cnt[idx[i]], 1);
}

// ---------------- single-block exclusive scan (chunked-serial + LDS scan) ----------------
__global__ __launch_bounds__(1024) void exscan_kernel(const int* __restrict__ in, int* __restrict__ out, int n)
{
  __shared__ int part[1024];
  int t = threadIdx.x;
  int per = (n + 1023) >> 10;
  int lo = t*per, hi = lo + per; if (hi > n) hi = n;
  int s = 0;
  for (int i = lo; i < hi; ++i) s += in[i];
  part[t] = s;
  __syncthreads();
  for (int ofs = 1; ofs < 1024; ofs <<= 1) {
    int v = (t >= ofs) ? part[t-ofs] : 0;
    __syncthreads();
    part[t] += v;
    __syncthreads();
  }
  int base = part[t] - s;   // exclusive prefix of this thread's chunk
  for (int i = lo; i < hi; ++i) { out[i] = base; base += in[i]; }
  if (t == 1023) out[n] = part[1023];
}

// ---------------- CSR scatter ----------------
__global__ void scatter_kernel(const int* __restrict__ src, const int* __restrict__ dst,
    const int* __restrict__ off, int* __restrict__ cursor, int* __restrict__ csr, int E)
{
  int i = blockIdx.x*blockDim.x + threadIdx.x;
  int stride = gridDim.x*blockDim.x;
  for (; i < E; i += stride) {
    int d = dst[i];
    int pos = off[d] + atomicAdd(&cursor[d], 1);
    csr[pos] = src[i];
  }
}

// ---------------- GAT aggregation per node + bias + BN + ReLU (+gate) ----------------
// C = channels/head (16 or 32), CP = channels per lane (F/64), GATE: compute pooling gate
template<int C, int CP, bool GATE>
__global__ __launch_bounds__(64) void gat_agg_kernel(
    const float* __restrict__ xh, const float* __restrict__ a_src, const float* __restrict__ a_dst,
    const int* __restrict__ off, const int* __restrict__ csr,
    const float* __restrict__ bias, const float* __restrict__ bng, const float* __restrict__ bnb,
    const float* __restrict__ bnrm, const float* __restrict__ bnrv,
    const float* __restrict__ gateW, const float* __restrict__ gateB,
    float* __restrict__ hout, float* __restrict__ gate, int N)
{
  constexpr int F = 64*CP;
  int n = blockIdx.x;
  if (n >= N) return;
  int lane = threadIdx.x;
  int lo = off[n], hi = off[n+1];
  const float4* as4 = (const float4*)a_src;
  const float4* ad4 = (const float4*)a_dst;
  float4 asn = as4[n], adn = ad4[n];
  // self-loop scores
  float e0s = leaky(asn.x+adn.x), e1s = leaky(asn.y+adn.y);
  float e2s = leaky(asn.z+adn.z), e3s = leaky(asn.w+adn.w);
  // phase A: per-head max over incoming edges (strided over lanes)
  float m0=e0s, m1=e1s, m2=e2s, m3=e3s;
  for (int k = lo+lane; k < hi; k += 64) {
    int s = csr[k];
    float4 a = as4[s];
    m0 = fmaxf(m0, leaky(a.x+adn.x));
    m1 = fmaxf(m1, leaky(a.y+adn.y));
    m2 = fmaxf(m2, leaky(a.z+adn.z));
    m3 = fmaxf(m3, leaky(a.w+adn.w));
  }
  #pragma unroll
  for (int msk = 1; msk < 64; msk <<= 1) {
    m0 = fmaxf(m0, __shfl_xor(m0, msk)); m1 = fmaxf(m1, __shfl_xor(m1, msk));
    m2 = fmaxf(m2, __shfl_xor(m2, msk)); m3 = fmaxf(m3, __shfl_xor(m3, msk));
  }
  // phase B: sum of exp
  float s0=0.f, s1=0.f, s2=0.f, s3=0.f;
  for (int k = lo+lane; k < hi; k += 64) {
    int s = csr[k];
    float4 a = as4[s];
    s0 += __expf(leaky(a.x+adn.x)-m0);
    s1 += __expf(leaky(a.y+adn.y)-m1);
    s2 += __expf(leaky(a.z+adn.z)-m2);
    s3 += __expf(leaky(a.w+adn.w)-m3);
  }
  #pragma unroll
  for (int msk = 1; msk < 64; msk <<= 1) {
    s0 += __shfl_xor(s0, msk); s1 += __shfl_xor(s1, msk);
    s2 += __shfl_xor(s2, msk); s3 += __shfl_xor(s3, msk);
  }
  s0 += __expf(e0s-m0); s1 += __expf(e1s-m1); s2 += __expf(e2s-m2); s3 += __expf(e3s-m3);
  float i0 = 1.f/(s0+1e-16f), i1 = 1.f/(s1+1e-16f), i2 = 1.f/(s2+1e-16f), i3 = 1.f/(s3+1e-16f);

  if constexpr (CP == 1) {
    int hh = lane >> 4;            // C=16: lane owns channel f=lane, head hh
    float mh  = sel4(hh, m0, m1, m2, m3);
    float adh = sel4(hh, adn.x, adn.y, adn.z, adn.w);
    float esh = sel4(hh, e0s, e1s, e2s, e3s);
    float acc = __expf(esh-mh) * xh[(size_t)n*F + lane];
    for (int k = lo; k < hi; ++k) {
      int s = csr[k];
      float4 a = as4[s];
      float ah = sel4(hh, a.x, a.y, a.z, a.w);
      acc += __expf(leaky(ah+adh)-mh) * xh[(size_t)s*F + lane];
    }
    float ih = sel4(hh, i0, i1, i2, i3);
    float r = acc*ih + bias[lane];
    r = (r - bnrm[lane]) * rsqrtf(bnrv[lane]+BN_EPS_F) * bng[lane] + bnb[lane];
    r = fmaxf(r, 0.f);
    hout[(size_t)n*F + lane] = r;
  } else {
    // C=32: lane owns f=lane (heads 0/1) and f=lane+64 (heads 2/3)
    bool hi32 = (lane & 32) != 0;
    float mh0 = hi32? m1:m0,        mh1 = hi32? m3:m2;
    float adh0 = hi32? adn.y:adn.x, adh1 = hi32? adn.w:adn.z;
    float es0 = hi32? e1s:e0s,      es1 = hi32? e3s:e2s;
    float acc0 = __expf(es0-mh0) * xh[(size_t)n*F + lane];
    float acc1 = __expf(es1-mh1) * xh[(size_t)n*F + lane + 64];
    for (int k = lo; k < hi; ++k) {
      int s = csr[k];
      float4 a = as4[s];
      float ah0 = hi32? a.y : a.x;
      float ah1 = hi32? a.w : a.z;
      acc0 += __expf(leaky(ah0+adh0)-mh0) * xh[(size_t)s*F + lane];
      acc1 += __expf(leaky(ah1+adh1)-mh1) * xh[(size_t)s*F + lane + 64];
    }
    float ih0 = hi32? i1:i0, ih1 = hi32? i3:i2;
    float r0 = acc0*ih0 + bias[lane];
    r0 = (r0 - bnrm[lane]) * rsqrtf(bnrv[lane]+BN_EPS_F) * bng[lane] + bnb[lane];
    r0 = fmaxf(r0, 0.f);
    float r1 = acc1*ih1 + bias[lane+64];
    r1 = (r1 - bnrm[lane+64]) * rsqrtf(bnrv[lane+64]+BN_EPS_F) * bng[lane+64] + bnb[lane+64];
    r1 = fmaxf(r1, 0.f);
    hout[(size_t)n*F + lane] = r0;
    hout[(size_t)n*F + lane + 64] = r1;
    if constexpr (GATE) {
      float gl = r0*gateW[lane] + r1*gateW[lane+64];
      #pragma unroll
      for (int msk = 1; msk < 64; msk <<= 1) gl += __shfl_xor(gl, msk);
      if (lane == 0) gate[n] = gl + gateB[0];
    }
  }
}

// ---------------- per-graph attention pooling + MLP heads ----------------
__global__ __launch_bounds__(128) void pool_kernel(
    const float* __restrict__ h2, const float* __restrict__ gate, const int* __restrict__ goff,
    const float* __restrict__ fc1W, const float* __restrict__ fc1b,
    const float* __restrict__ valW, const float* __restrict__ valb,
    const float* __restrict__ advW, const float* __restrict__ advb,
    float* __restrict__ out)
{
  int g = blockIdx.x, t = threadIdx.x;
  int lo = goff[g], hi = goff[g+1];
  __shared__ float red[2];
  __shared__ float pld[128];
  __shared__ float zs[32];
  __shared__ float sval;
  __shared__ float adv_s[16];

  // max gate
  float m = -3.4e38f;
  for (int n = lo+t; n < hi; n += 128) m = fmaxf(m, gate[n]);
  #pragma unroll
  for (int msk = 1; msk < 64; msk <<= 1) m = fmaxf(m, __shfl_xor(m, msk));
  if ((t & 63) == 0) red[t >> 6] = m;
  __syncthreads();
  m = fmaxf(red[0], red[1]);
  __syncthreads();
  // sum exp
  float sl = 0.f;
  for (int n = lo+t; n < hi; n += 128) sl += __expf(gate[n]-m);
  #pragma unroll
  for (int msk = 1; msk < 64; msk <<= 1) sl += __shfl_xor(sl, msk);
  if ((t & 63) == 0) red[t >> 6] = sl;
  __syncthreads();
  float s = red[0] + red[1];
  // weighted sum: thread t owns feature t
  float acc = 0.f;
  for (int n = lo; n < hi; ++n) {
    float w = __expf(gate[n]-m);
    acc += w * h2[(size_t)n*128 + t];
  }
  pld[t] = acc / (s + 1e-16f);
  __syncthreads();
  // z = relu(pooled @ fc1W + b)
  if (t < 32) {
    float z = fc1b[t];
    #pragma unroll 4
    for (int k = 0; k < 128; ++k) z += pld[k]*fc1W[k*32 + t];
    zs[t] = fmaxf(z, 0.f);
  }
  __syncthreads();
  if (t < 32) {
    float pv = zs[t]*valW[t];
    #pragma unroll
    for (int msk = 1; msk < 32; msk <<= 1) pv += __shfl_xor(pv, msk);
    if (t == 0) sval = pv + valb[0];
  }
  if (t < 16) {
    float a = advb[t];
    #pragma unroll
    for (int k = 0; k < 32; ++k) a += zs[k]*advW[k*16 + t];
    adv_s[t] = a;
  }
  __syncthreads();
  if (t < 16) {
    float amean = adv_s[t];
    #pragma unroll
    for (int msk = 1; msk < 16; msk <<= 1) amean += __shfl_xor(amean, msk);
    amean *= (1.f/16.f);
    out[g*16 + t] = sval + adv_s[t] - amean;
  }
}

extern "C" void kernel_launch(void* const* d_in, const int* in_sizes, int n_in,
                              void* d_out, int out_size, void* d_ws, size_t ws_size,
                              hipStream_t stream)
{
  const float* x     = (const float*)d_in[0];
  const int*   eidx  = (const int*)  d_in[1];
  const int*   batch = (const int*)  d_in[2];
  const float* W1    = (const float*)d_in[3];
  const float* as1w  = (const float*)d_in[4];
  const float* ad1w  = (const float*)d_in[5];
  const float* b1    = (const float*)d_in[6];
  const float* bn1g  = (const float*)d_in[7];
  const float* bn1b  = (const float*)d_in[8];
  const float* bn1rm = (const float*)d_in[9];
  const float* bn1rv = (const float*)d_in[10];
  const float* W2    = (const float*)d_in[11];
  const float* as2w  = (const float*)d_in[12];
  const float* ad2w  = (const float*)d_in[13];
  const float* b2    = (const float*)d_in[14];
  const float* bn2g  = (const float*)d_in[15];
  const float* bn2b  = (const float*)d_in[16];
  const float* bn2rm = (const float*)d_in[17];
  const float* bn2rv = (const float*)d_in[18];
  const float* gateW = (const float*)d_in[19];
  const float* gateB = (const float*)d_in[20];
  const float* fc1W  = (const float*)d_in[21];
  const float* fc1b  = (const float*)d_in[22];
  const float* valW  = (const float*)d_in[23];
  const float* valb  = (const float*)d_in[24];
  const float* advW  = (const float*)d_in[25];
  const float* advb  = (const float*)d_in[26];

  int N = in_sizes[0] / 32;
  int E = in_sizes[1] / 2;
  const int* esrc = eidx;
  const int* edst = eidx + E;

  float* ws = (float*)d_ws;
  size_t o = 0;
  float* xh1 = ws + o; o += (size_t)N*64;
  float* xh2 = ws + o; o += (size_t)N*128;
  float* as1 = ws + o; o += (size_t)N*4;
  float* ad1 = ws + o; o += (size_t)N*4;
  float* as2 = ws + o; o += (size_t)N*4;
  float* ad2 = ws + o; o += (size_t)N*4;
  float* h1  = ws + o; o += (size_t)N*64;
  float* h2  = ws + o; o += (size_t)N*128;
  float* gate = ws + o; o += (size_t)N;
  int* ib     = (int*)(ws + o);
  int* deg    = ib;                        // N
  int* cursor = ib + N;                    // N
  int* gcnt   = ib + 2*(size_t)N;          // NUM_G   (deg..gcnt zeroed together)
  int* off    = ib + 2*(size_t)N + NUM_G;  // N+1
  int* goff   = off + (N+1);               // NUM_G+1
  int* csr    = goff + (NUM_G+1);          // E

  hipMemsetAsync(deg, 0, (size_t)(2*(size_t)N + NUM_G)*sizeof(int), stream);

  lin1_kernel<<<(N+15)/16, 256, 0, stream>>>(x, W1, as1w, ad1w, xh1, as1, ad1, N);
  hist_kernel<<<1024, 256, 0, stream>>>(edst, deg, E);
  hist_kernel<<<256, 256, 0, stream>>>(batch, gcnt, N);
  exscan_kernel<<<1, 1024, 0, stream>>>(deg, off, N);
  exscan_kernel<<<1, 1024, 0, stream>>>(gcnt, goff, NUM_G);
  scatter_kernel<<<1024, 256, 0, stream>>>(esrc, edst, off, cursor, csr, E);
  gat_agg_kernel<16,1,false><<<N, 64, 0, stream>>>(xh1, as1, ad1, off, csr,
      b1, bn1g, bn1b, bn1rm, bn1rv, nullptr, nullptr, h1, nullptr, N);
  lin2_kernel<<<(N+15)/16, 256, 0, stream>>>(h1, W2, as2w, ad2w, xh2, as2, ad2, N);
  gat_agg_kernel<32,2,true><<<N, 64, 0, stream>>>(xh2, as2, ad2, off, csr,
      b2, bn2g, bn2b, bn2rm, bn2rv, gateW, gateB, h2, gate, N);
  pool_kernel<<<NUM_G, 128, 0, stream>>>(h2, gate, goff, fc1W, fc1b, valW, valb, advW, advb,
      (float*)d_out);
}